// Round 2
// baseline (490.442 us; speedup 1.0000x reference)
//
#include <hip/hip_runtime.h>

// Problem constants
#define NROW 16384   // B*H*W
#define KC   2048    // n_codes
#define DIM  512     // embedding dim

typedef __attribute__((ext_vector_type(8))) short  short8;
typedef __attribute__((ext_vector_type(4))) float  floatx4;

// ---------------- helpers ----------------

__device__ __forceinline__ unsigned short f2bf(float f) {
  // round-to-nearest-even fp32 -> bf16 (finite values)
  unsigned int u = __float_as_uint(f);
  u += 0x7fffu + ((u >> 16) & 1u);
  return (unsigned short)(u >> 16);
}

// async global->LDS, 16B per lane (dest must be linear: base + lane*16)
#define GLDS(gsrc, ldst) __builtin_amdgcn_global_load_lds( \
    (const __attribute__((address_space(1))) unsigned int*)(gsrc), \
    (__attribute__((address_space(3))) unsigned int*)(ldst), 16, 0, 0)

// ---------------- K1: merged codebook-normalize + per-sample norms ----------------
// blocks [0, KC): codebook row k -> cb_bf (bf16 normalized) + csq
// blocks [KC, KC+256): z column norms for 64 p's each (b = blk>>4, pc = blk&15)
__global__ void k_prep(const float* __restrict__ emb,
                       unsigned short* __restrict__ cb_bf,
                       float* __restrict__ csq,
                       const float* __restrict__ z,
                       float* __restrict__ rnorm) {
  __shared__ float red4[4];
  __shared__ float redp[4][64];
  if (blockIdx.x < KC) {
    const int k = blockIdx.x;
    const int t = threadIdx.x;        // 256
    const float* row = emb + (size_t)k * DIM;
    float v0 = row[t], v1 = row[t + 256];
    float ss = v0 * v0 + v1 * v1;
#pragma unroll
    for (int o = 32; o; o >>= 1) ss += __shfl_xor(ss, o, 64);
    if ((t & 63) == 0) red4[t >> 6] = ss;
    __syncthreads();
    float tot = red4[0] + red4[1] + red4[2] + red4[3];
    float r = 1.0f / fmaxf(sqrtf(tot), 1e-12f);
    cb_bf[(size_t)k * DIM + t]       = f2bf(v0 * r);
    cb_bf[(size_t)k * DIM + t + 256] = f2bf(v1 * r);
    if (t == 0) csq[k] = tot * r * r;   // sum of squares of normalized row (~1)
  } else {
    const int blk = blockIdx.x - KC;    // 0..255
    const int b  = blk >> 4;            // 16
    const int pc = blk & 15;            // 16 chunks of 64 p's
    const int tx = threadIdx.x & 63;
    const int ty = threadIdx.x >> 6;    // 0..3
    const int p  = pc * 64 + tx;
    const float* zp = z + (size_t)b * (DIM * 1024) + p;
    float ss = 0.f;
    for (int d = ty; d < DIM; d += 4) {
      float v = zp[(size_t)d * 1024];
      ss += v * v;
    }
    redp[ty][tx] = ss;
    __syncthreads();
    if (ty == 0) {
      float tot = redp[0][tx] + redp[1][tx] + redp[2][tx] + redp[3][tx];
      rnorm[b * 1024 + p] = 1.0f / fmaxf(sqrtf(tot), 1e-12f);
    }
  }
}

// ---------------- K2: transpose z [B,D,HW] -> flatT [N,D] + bf16 z_norm ----------------
__global__ void k_transpose(const float* __restrict__ z, const float* __restrict__ rnorm,
                            float* __restrict__ flatT, unsigned short* __restrict__ zbf) {
  __shared__ float tile[32][33];
  __shared__ float srn[32];
  const int dt = blockIdx.x;   // 0..15  (D/32)
  const int pt = blockIdx.y;   // 0..31  (HW/32)
  const int b  = blockIdx.z;   // 0..15
  const int tx = threadIdx.x & 31;
  const int ty = threadIdx.x >> 5;     // 0..7
  if (threadIdx.x < 32) srn[threadIdx.x] = rnorm[b * 1024 + pt * 32 + threadIdx.x];
  const size_t zb = (size_t)b * (DIM * 1024);
#pragma unroll
  for (int i = 0; i < 4; ++i) {
    int d = dt * 32 + ty + i * 8;
    int p = pt * 32 + tx;
    tile[ty + i * 8][tx] = z[zb + (size_t)d * 1024 + p];
  }
  __syncthreads();
#pragma unroll
  for (int i = 0; i < 4; ++i) {
    int p = pt * 32 + ty + i * 8;
    int d = dt * 32 + tx;
    float v = tile[tx][ty + i * 8];
    size_t o = (size_t)(b * 1024 + p) * DIM + d;
    flatT[o] = v;
    zbf[o]   = f2bf(v * srn[ty + i * 8]);
  }
}

// ---------------- K3: bf16 MFMA GEMM, writes t = 2*S - csq ----------------
// 128x128 tile, BK=64, 4 waves of 64x64, 16x16x32 MFMA.
// m97-style staging: global_load_lds (16B/lane) into LINEAR LDS [128][64].
__global__ __launch_bounds__(256) void k_gemm(const unsigned short* __restrict__ A,
                                              const unsigned short* __restrict__ Bm,
                                              const float* __restrict__ csq,
                                              float* __restrict__ T) {
  __shared__ alignas(16) unsigned short smA[128 * 64];
  __shared__ alignas(16) unsigned short smB[128 * 64];
  const int tid  = threadIdx.x;
  const int wid  = tid >> 6;
  const int lane = tid & 63;
  const int m0 = blockIdx.x * 128;
  const int n0 = blockIdx.y * 128;
  const int wm = (wid >> 1) * 64;
  const int wn = (wid & 1) * 64;

  floatx4 acc[4][4];
  const floatx4 z4 = {0.f, 0.f, 0.f, 0.f};
#pragma unroll
  for (int mi = 0; mi < 4; ++mi)
#pragma unroll
    for (int ni = 0; ni < 4; ++ni) acc[mi][ni] = z4;

  const int srow = tid >> 3;        // 0..31, +i*32 per issue
  const int scol = (tid & 7) * 8;   // short offset within 64-wide row
  const unsigned short* Abase = A  + (size_t)(m0 + srow) * DIM + scol;
  const unsigned short* Bbase = Bm + (size_t)(n0 + srow) * DIM + scol;

  for (int kt = 0; kt < 8; ++kt) {
    const int kb = kt * 64;
#pragma unroll
    for (int i = 0; i < 4; ++i) {
      GLDS(Abase + kb + (size_t)i * 32 * DIM, &smA[i * 2048 + tid * 8]);
      GLDS(Bbase + kb + (size_t)i * 32 * DIM, &smB[i * 2048 + tid * 8]);
    }
    __syncthreads();   // drains vmcnt for the direct-to-LDS loads
    const int q  = lane >> 4;
    const int mr = lane & 15;
#pragma unroll
    for (int kk = 0; kk < 2; ++kk) {
      const int cb = (kk * 4 + q) * 8;
      short8 af[4], bfr[4];
#pragma unroll
      for (int mi = 0; mi < 4; ++mi)
        af[mi] = *(const short8*)&smA[(wm + mi * 16 + mr) * 64 + cb];
#pragma unroll
      for (int ni = 0; ni < 4; ++ni)
        bfr[ni] = *(const short8*)&smB[(wn + ni * 16 + mr) * 64 + cb];
#pragma unroll
      for (int mi = 0; mi < 4; ++mi)
#pragma unroll
        for (int ni = 0; ni < 4; ++ni)
          acc[mi][ni] = __builtin_amdgcn_mfma_f32_16x16x32_bf16(af[mi], bfr[ni], acc[mi][ni], 0, 0, 0);
    }
    __syncthreads();
  }

  // epilogue: C/D layout col = lane&15, row = (lane>>4)*4 + reg; fuse t = 2S - csq
  const int col = lane & 15;
  const int rq  = (lane >> 4) * 4;
  float csqv[4];
#pragma unroll
  for (int ni = 0; ni < 4; ++ni) csqv[ni] = csq[n0 + wn + ni * 16 + col];
#pragma unroll
  for (int mi = 0; mi < 4; ++mi)
#pragma unroll
    for (int r = 0; r < 4; ++r) {
      size_t rowoff = (size_t)(m0 + wm + mi * 16 + rq + r) * KC;
#pragma unroll
      for (int ni = 0; ni < 4; ++ni)
        T[rowoff + n0 + wn + ni * 16 + col] = 2.0f * acc[mi][ni][r] - csqv[ni];
    }
}

// ---------------- K4: streaming softmax (fixed-reference exp) + candidates ----------------
// t = 2*dot - csq with unit vectors => t <= ~1.03 bounded. Use M0 = 1.0 as the
// exp reference: dp = exp(t-1)/sum(exp(t-1)) == softmax(t). No max pre-pass.
// Candidate margin in exp domain: ev >= EMX * exp(-MARGIN) <=> t >= tmax - MARGIN.
#define EXP_MARGIN 0.980198673f   // exp(-0.02); 0.02 covers worst-case bf16 dot error

__global__ void k_softmax(float* __restrict__ T,
                          int* __restrict__ cand_cnt, int* __restrict__ cand_list) {
  const int n = blockIdx.x;
  const int t = threadIdx.x;  // 256
  const int lane = t & 63, wid = t >> 6;
  float* row = T + (size_t)n * KC;
  // vectorized read: thread t owns k = t*8 .. t*8+7
  floatx4 v0 = *(const floatx4*)&row[t * 8];
  floatx4 v1 = *(const floatx4*)&row[t * 8 + 4];
  float ev[8];
  float mx = 0.f, sum = 0.f;
#pragma unroll
  for (int j = 0; j < 4; ++j) {
    ev[j]     = __expf(v0[j] - 1.0f);
    ev[j + 4] = __expf(v1[j] - 1.0f);
  }
#pragma unroll
  for (int j = 0; j < 8; ++j) {
    mx = fmaxf(mx, ev[j]);
    sum += ev[j];
  }
#pragma unroll
  for (int o = 32; o; o >>= 1) {
    mx  = fmaxf(mx, __shfl_xor(mx, o, 64));
    sum += __shfl_xor(sum, o, 64);
  }
  __shared__ float redm[4], reds[4];
  __shared__ int s_cnt;
  if (t == 0) s_cnt = 0;
  if (lane == 0) { redm[wid] = mx; reds[wid] = sum; }
  __syncthreads();
  const float EMX = fmaxf(fmaxf(redm[0], redm[1]), fmaxf(redm[2], redm[3]));
  const float inv = 1.0f / (reds[0] + reds[1] + reds[2] + reds[3]);
  const float thr = EMX * EXP_MARGIN;
#pragma unroll
  for (int j = 0; j < 8; ++j) {
    if (ev[j] >= thr) {
      int p = atomicAdd(&s_cnt, 1);
      if (p < 16) cand_list[n * 16 + p] = t * 8 + j;
    }
  }
  floatx4 w0, w1;
#pragma unroll
  for (int j = 0; j < 4; ++j) { w0[j] = ev[j] * inv; w1[j] = ev[j + 4] * inv; }
  *(floatx4*)&row[t * 8]     = w0;
  *(floatx4*)&row[t * 8 + 4] = w1;
  __syncthreads();
  if (t == 0) cand_cnt[n] = (s_cnt > 16) ? -1 : s_cnt;
}

// ---------------- K5: index fixup (exact fp64) + EMA stats + commitment partials ----
__global__ void k_pick(const float* __restrict__ flatT, const float* __restrict__ emb,
                       const float* __restrict__ rnorm,
                       const int* __restrict__ cand_cnt, const int* __restrict__ cand_list,
                       int* __restrict__ idx, float* __restrict__ enc_sum,
                       float* __restrict__ n_total, double* __restrict__ cl_part) {
  const int n = blockIdx.x;
  const int t = threadIdx.x;  // 256
  const int lane = t & 63, wid = t >> 6;
  __shared__ int s_j;
  const int c = cand_cnt[n];
  if (c == 1) {
    if (t == 0) s_j = cand_list[n * 16];
  } else if (wid == 0) {
    const float* zr = flatT + (size_t)n * DIM;
    double zs = 0.0;
    for (int d = lane; d < DIM; d += 64) { double v = zr[d]; zs += v * v; }
#pragma unroll
    for (int o = 32; o; o >>= 1) zs += __shfl_xor(zs, o, 64);
    double zn = fmax(sqrt(zs), 1e-12);
    double best = 1e300;
    int bestk = 0x7fffffff;
    const int m = (c < 0) ? KC : c;
    for (int ci = 0; ci < m; ++ci) {
      int k = (c < 0) ? ci : cand_list[n * 16 + ci];
      const float* er = emb + (size_t)k * DIM;
      double cs = 0.0, dot = 0.0;
      for (int d = lane; d < DIM; d += 64) {
        double e = er[d], zv = zr[d];
        cs += e * e; dot += zv * e;
      }
#pragma unroll
      for (int o = 32; o; o >>= 1) { cs += __shfl_xor(cs, o, 64); dot += __shfl_xor(dot, o, 64); }
      double cn = fmax(sqrt(cs), 1e-12);
      double score = cs / (cn * cn) - 2.0 * dot / (zn * cn);  // distance minus row-const zsq
      if (score < best || (score == best && k < bestk)) { best = score; bestk = k; }
    }
    if (lane == 0) s_j = bestk;
  }
  __syncthreads();
  const int j = s_j;
  if (t == 0) idx[n] = j;

  const float rn = rnorm[n], rj = rnorm[j];
  const float* zr  = flatT + (size_t)n * DIM;
  const float* zjr = flatT + (size_t)j * DIM;
  double cl = 0.0;
#pragma unroll
  for (int i = 0; i < 2; ++i) {
    int d = t + i * 256;
    float zv  = zr[d] * rn;
    float evv = zjr[d] * rj;
    float df  = zv - evv;
    cl += (double)df * (double)df;
    atomicAdd(&enc_sum[(size_t)j * DIM + d], zv);
  }
#pragma unroll
  for (int o = 32; o; o >>= 1) cl += __shfl_xor(cl, o, 64);
  __shared__ double redd[4];
  if (lane == 0) redd[wid] = cl;
  __syncthreads();
  if (t == 0) {
    cl_part[n] = redd[0] + redd[1] + redd[2] + redd[3];
    atomicAdd(&n_total[j], 1.0f);
  }
}

// ---------------- K6: fused tail — z_avg_new, N_new, embeddings_new, |.| partials ----
// n = sum(N_new) = 0.99*sum(N_buf) + 0.01*NROW  (sum of one-hot counts == NROW exactly)
__global__ void k_tail(const float* __restrict__ za, const float* __restrict__ es,
                       const float* __restrict__ Nb, const float* __restrict__ ntot,
                       float* __restrict__ out_zav, float* __restrict__ outN,
                       float* __restrict__ out_emb, double* __restrict__ cbs_part) {
  const int k = blockIdx.x;   // 2048
  const int t = threadIdx.x;  // 256
  const int lane = t & 63, wid = t >> 6;
  // redundant per-block reduce of n (8 KB, L2-resident)
  float s = 0.f;
#pragma unroll
  for (int i = 0; i < 8; ++i) {
    int kk = t + i * 256;
    s += 0.99f * Nb[kk] + 0.01f * ntot[kk];
  }
#pragma unroll
  for (int o = 32; o; o >>= 1) s += __shfl_xor(s, o, 64);
  __shared__ float redn[4];
  if (lane == 0) redn[wid] = s;
  __syncthreads();
  const float nv = redn[0] + redn[1] + redn[2] + redn[3];
  const float Nn = 0.99f * Nb[k] + 0.01f * ntot[k];
  if (t == 0) outN[k] = Nn;
  const float w = (Nn + 1e-5f) / (nv + 0.02048f) * nv;
  double a = 0.0;
#pragma unroll
  for (int i = 0; i < 2; ++i) {
    size_t gi = (size_t)k * DIM + t + i * 256;
    float zv = 0.99f * za[gi] + 0.01f * es[gi];
    out_zav[gi] = zv;
    float e = zv / w;
    out_emb[gi] = e;
    a += (double)fabsf(e);
  }
#pragma unroll
  for (int o = 32; o; o >>= 1) a += __shfl_xor(a, o, 64);
  __shared__ double red[4];
  if (lane == 0) red[wid] = a;
  __syncthreads();
  if (t == 0) cbs_part[k] = red[0] + red[1] + red[2] + red[3];
}

// ---------------- K7: q gather + (extra block) final scalar reductions ----------------
__global__ void k_q(const float* __restrict__ flatT, const float* __restrict__ rnorm,
                    const int* __restrict__ idx, float* __restrict__ out,
                    const double* __restrict__ cl_part, const double* __restrict__ cbs_part) {
  if (blockIdx.x == 32768) {
    const int t = threadIdx.x;  // 256
    double cl = 0.0, cb = 0.0;
    for (int i = t; i < NROW; i += 256) cl += cl_part[i];
    for (int i = t; i < KC; i += 256) cb += cbs_part[i];
#pragma unroll
    for (int o = 32; o; o >>= 1) { cl += __shfl_xor(cl, o, 64); cb += __shfl_xor(cb, o, 64); }
    __shared__ double redc[4], redb[4];
    if ((t & 63) == 0) { redc[t >> 6] = cl; redb[t >> 6] = cb; }
    __syncthreads();
    if (t == 0) {
      double clm = (redc[0] + redc[1] + redc[2] + redc[3]) / 8388608.0;  // N*D
      double cbs = redb[0] + redb[1] + redb[2] + redb[3];
      out[41943040] = (float)clm;          // commitment_loss
      out[41943041] = (float)(0.25 * clm); // loss = BETA * commitment_loss
      out[41943042] = (float)cbs;          // codebook_sum
    }
    return;
  }
  const int o = blockIdx.x * 256 + threadIdx.x;
  const int b = o >> 19;            // D*H*W = 2^19
  const int d = (o >> 10) & 511;
  const int p = o & 1023;
  const int j = idx[(b << 10) + p];
  out[o] = flatT[(size_t)j * DIM + d] * rnorm[j];
}

// ---------------- launcher ----------------
extern "C" void kernel_launch(void* const* d_in, const int* in_sizes, int n_in,
                              void* d_out, int out_size, void* d_ws, size_t ws_size,
                              hipStream_t stream) {
  const float* z   = (const float*)d_in[0];
  const float* emb = (const float*)d_in[1];
  const float* Nb  = (const float*)d_in[2];
  const float* za  = (const float*)d_in[3];
  float* out = (float*)d_out;
  char*  ws  = (char*)d_ws;

  // workspace layout (bytes)
  float*          flatT     = (float*)(ws + 0);                 // 33554432
  unsigned short* cb_bf     = (unsigned short*)(ws + 33554432); // 2097152
  float*          csq       = (float*)(ws + 35651584);          // 8192
  float*          rnorm     = (float*)(ws + 35659776);          // 65536
  int*            idx       = (int*)(ws + 35725312);            // 65536
  int*            cand_cnt  = (int*)(ws + 35790848);            // 65536
  int*            cand_list = (int*)(ws + 35856384);            // 1048576
  double*         cl_part   = (double*)(ws + 36904960);         // 131072
  double*         cbs_part  = (double*)(ws + 37036032);         // 16384
  float*          enc_sum   = (float*)(ws + 37052416);          // 4194304 (zeroed)
  float*          n_total   = (float*)(ws + 41246720);          // 8192    (zeroed)

  // d_out regions (floats): q[0..8388608), dp[8388608..41943040),
  // scalars[41943040..3), emb_new[41943043), N_new[42991619), z_avg_new[42993667)
  unsigned short* z_bf  = (unsigned short*)out;   // q region reused as bf16 scratch
  float* S        = out + 8388608;
  float* out_emb  = out + 41943043;
  float* out_N    = out + 42991619;
  float* out_zav  = out + 42993667;

  hipMemsetAsync(ws + 37052416, 0, 4202496, stream);   // enc_sum + n_total

  k_prep     <<<KC + 256, 256, 0, stream>>>(emb, cb_bf, csq, z, rnorm);
  k_transpose<<<dim3(16, 32, 16), 256, 0, stream>>>(z, rnorm, flatT, z_bf);
  k_gemm     <<<dim3(NROW / 128, KC / 128), 256, 0, stream>>>(z_bf, cb_bf, csq, S);
  k_softmax  <<<NROW, 256, 0, stream>>>(S, cand_cnt, cand_list);
  k_pick     <<<NROW, 256, 0, stream>>>(flatT, emb, rnorm, cand_cnt, cand_list, idx, enc_sum, n_total, cl_part);
  k_tail     <<<KC, 256, 0, stream>>>(za, enc_sum, Nb, n_total, out_zav, out_N, out_emb, cbs_part);
  k_q        <<<32769, 256, 0, stream>>>(flatT, rnorm, idx, out, cl_part, cbs_part);
}

// Round 3
// 415.600 us; speedup vs baseline: 1.1801x; 1.1801x over previous
//
#include <hip/hip_runtime.h>

// Problem constants
#define NROW 16384   // B*H*W
#define KC   2048    // n_codes
#define DIM  512     // embedding dim

typedef __attribute__((ext_vector_type(8))) short  short8;
typedef __attribute__((ext_vector_type(4))) float  floatx4;

// ---------------- helpers ----------------

__device__ __forceinline__ unsigned short f2bf(float f) {
  // round-to-nearest-even fp32 -> bf16 (finite values)
  unsigned int u = __float_as_uint(f);
  u += 0x7fffu + ((u >> 16) & 1u);
  return (unsigned short)(u >> 16);
}

// ---------------- K1: codebook row-normalize -> bf16 + csq ----------------
__global__ void k_cbnorm(const float* __restrict__ emb,
                         unsigned short* __restrict__ cb_bf,
                         float* __restrict__ csq) {
  const int k = blockIdx.x;
  const int t = threadIdx.x;        // 256
  const float* row = emb + (size_t)k * DIM;
  float v0 = row[t], v1 = row[t + 256];
  float ss = v0 * v0 + v1 * v1;
#pragma unroll
  for (int o = 32; o; o >>= 1) ss += __shfl_xor(ss, o, 64);
  __shared__ float red[4];
  if ((t & 63) == 0) red[t >> 6] = ss;
  __syncthreads();
  float tot = red[0] + red[1] + red[2] + red[3];
  float r = 1.0f / fmaxf(sqrtf(tot), 1e-12f);
  cb_bf[(size_t)k * DIM + t]       = f2bf(v0 * r);
  cb_bf[(size_t)k * DIM + t + 256] = f2bf(v1 * r);
  if (t == 0) csq[k] = tot * r * r;   // sum of squares of normalized row (~1)
}

// ---------------- K2: transpose z [B,D,HW] -> flatT [N,D] ----------------
__global__ void k_transpose(const float* __restrict__ z, float* __restrict__ flatT) {
  __shared__ float tile[32][33];
  const int dt = blockIdx.x;   // 0..15  (D/32)
  const int pt = blockIdx.y;   // 0..31  (HW/32)
  const int b  = blockIdx.z;   // 0..15
  const int tx = threadIdx.x & 31;
  const int ty = threadIdx.x >> 5;     // 0..7
  const size_t zb = (size_t)b * (DIM * 1024);
#pragma unroll
  for (int i = 0; i < 4; ++i) {
    int d = dt * 32 + ty + i * 8;
    int p = pt * 32 + tx;
    tile[ty + i * 8][tx] = z[zb + (size_t)d * 1024 + p];
  }
  __syncthreads();
#pragma unroll
  for (int i = 0; i < 4; ++i) {
    int p = pt * 32 + ty + i * 8;
    int d = dt * 32 + tx;
    flatT[(size_t)(b * 1024 + p) * DIM + d] = tile[tx][ty + i * 8];
  }
}

// ---------------- K3: z row norms + bf16 copy ----------------
__global__ void k_rownorm(const float* __restrict__ flatT,
                          float* __restrict__ rnorm,
                          unsigned short* __restrict__ zbf) {
  const int n = blockIdx.x;
  const int t = threadIdx.x;   // 256
  const float* row = flatT + (size_t)n * DIM;
  float v0 = row[t], v1 = row[t + 256];
  float ss = v0 * v0 + v1 * v1;
#pragma unroll
  for (int o = 32; o; o >>= 1) ss += __shfl_xor(ss, o, 64);
  __shared__ float red[4];
  if ((t & 63) == 0) red[t >> 6] = ss;
  __syncthreads();
  float tot = red[0] + red[1] + red[2] + red[3];
  float r = 1.0f / fmaxf(sqrtf(tot), 1e-12f);
  if (t == 0) rnorm[n] = r;
  zbf[(size_t)n * DIM + t]       = f2bf(v0 * r);
  zbf[(size_t)n * DIM + t + 256] = f2bf(v1 * r);
}

// ---------------- K4: bf16 MFMA GEMM  S[n,k] = z_norm . cb_norm ----------------
// 128x128 tile, BK=64, 4 waves of 64x64, 16x16x32 MFMA, XOR-swizzled LDS.
__global__ __launch_bounds__(256) void k_gemm(const unsigned short* __restrict__ A,
                                              const unsigned short* __restrict__ Bm,
                                              float* __restrict__ S) {
  __shared__ alignas(16) unsigned short smA[128 * 64];
  __shared__ alignas(16) unsigned short smB[128 * 64];
  const int tid  = threadIdx.x;
  const int wid  = tid >> 6;
  const int lane = tid & 63;
  const int m0 = blockIdx.x * 128;
  const int n0 = blockIdx.y * 128;
  const int wm = (wid >> 1) * 64;
  const int wn = (wid & 1) * 64;

  floatx4 acc[4][4];
  const floatx4 z4 = {0.f, 0.f, 0.f, 0.f};
#pragma unroll
  for (int mi = 0; mi < 4; ++mi)
#pragma unroll
    for (int ni = 0; ni < 4; ++ni) acc[mi][ni] = z4;

  const int srow_l = tid >> 3;  // +i*32 per staging issue
  const int spb    = tid & 7;

  for (int kt = 0; kt < 8; ++kt) {
    const int kbase = kt * 64;
    // stage A and B tiles (manual vectorized staging, swizzled layout:
    // physical 16B-block pb holds logical block lb = pb ^ (row & 7))
#pragma unroll
    for (int i = 0; i < 4; ++i) {
      int row = i * 32 + srow_l;
      int lb  = spb ^ (row & 7);
      const short8 va = *(const short8*)(A  + (size_t)(m0 + row) * DIM + kbase + lb * 8);
      const short8 vb = *(const short8*)(Bm + (size_t)(n0 + row) * DIM + kbase + lb * 8);
      *(short8*)&smA[i * 2048 + tid * 8] = va;
      *(short8*)&smB[i * 2048 + tid * 8] = vb;
    }
    __syncthreads();
#pragma unroll
    for (int kk = 0; kk < 2; ++kk) {
      const int q   = lane >> 4;
      const int mr  = lane & 15;
      const int lbq = kk * 4 + q;   // logical 8-elem block index in row
      short8 af[4], bfr[4];
#pragma unroll
      for (int mi = 0; mi < 4; ++mi) {
        int row = wm + mi * 16 + mr;
        int pb  = lbq ^ (row & 7);
        af[mi] = *(const short8*)&smA[row * 64 + pb * 8];
      }
#pragma unroll
      for (int ni = 0; ni < 4; ++ni) {
        int row = wn + ni * 16 + mr;
        int pb  = lbq ^ (row & 7);
        bfr[ni] = *(const short8*)&smB[row * 64 + pb * 8];
      }
#pragma unroll
      for (int mi = 0; mi < 4; ++mi)
#pragma unroll
        for (int ni = 0; ni < 4; ++ni)
          acc[mi][ni] = __builtin_amdgcn_mfma_f32_16x16x32_bf16(af[mi], bfr[ni], acc[mi][ni], 0, 0, 0);
    }
    __syncthreads();
  }

  // epilogue: C/D layout col = lane&15, row = (lane>>4)*4 + reg
  const int col = lane & 15;
  const int rq  = (lane >> 4) * 4;
#pragma unroll
  for (int mi = 0; mi < 4; ++mi)
#pragma unroll
    for (int r = 0; r < 4; ++r) {
      size_t rowoff = (size_t)(m0 + wm + mi * 16 + rq + r) * KC;
#pragma unroll
      for (int ni = 0; ni < 4; ++ni)
        S[rowoff + n0 + wn + ni * 16 + col] = acc[mi][ni][r];
    }
}

// ---------------- K5: softmax over codes (in-place) + argmin candidates ----------------
// logits t_k = 2*S - csq  (row-constant zsq cancels in softmax / argmin)
#define MARGIN_T 2.0e-2f   // covers worst-case bf16 dot error bound (~1e-2)

__global__ void k_softmax(float* __restrict__ S, const float* __restrict__ csq,
                          int* __restrict__ cand_cnt, int* __restrict__ cand_list) {
  const int n = blockIdx.x;
  const int t = threadIdx.x;  // 256
  float* row = S + (size_t)n * KC;
  float tv[8];
  float mx = -3.4e38f;
#pragma unroll
  for (int j = 0; j < 8; ++j) {
    int k = t + j * 256;
    tv[j] = 2.0f * row[k] - csq[k];
    mx = fmaxf(mx, tv[j]);
  }
#pragma unroll
  for (int o = 32; o; o >>= 1) mx = fmaxf(mx, __shfl_xor(mx, o, 64));
  __shared__ float redm[4];
  __shared__ float redsum[4];
  __shared__ int   s_cnt;
  __shared__ int   s_list[16];
  if (t == 0) s_cnt = 0;
  if ((t & 63) == 0) redm[t >> 6] = mx;
  __syncthreads();
  const float MX = fmaxf(fmaxf(redm[0], redm[1]), fmaxf(redm[2], redm[3]));
  float ev[8];
  float sum = 0.f;
#pragma unroll
  for (int j = 0; j < 8; ++j) {
    int k = t + j * 256;
    if (tv[j] >= MX - MARGIN_T) {
      int p = atomicAdd(&s_cnt, 1);
      if (p < 16) s_list[p] = k;
    }
    ev[j] = __expf(tv[j] - MX);
    sum += ev[j];
  }
#pragma unroll
  for (int o = 32; o; o >>= 1) sum += __shfl_xor(sum, o, 64);
  if ((t & 63) == 0) redsum[t >> 6] = sum;
  __syncthreads();
  const float inv = 1.0f / (redsum[0] + redsum[1] + redsum[2] + redsum[3]);
#pragma unroll
  for (int j = 0; j < 8; ++j) row[t + j * 256] = ev[j] * inv;
  if (t < 16 && t < s_cnt) cand_list[n * 16 + t] = s_list[t];
  if (t == 0) cand_cnt[n] = (s_cnt > 16) ? -1 : s_cnt;
}

// ---------------- K6: exact fp64 argmin among candidates ----------------
__global__ void k_fixup(const float* __restrict__ flatT, const float* __restrict__ emb,
                        const int* __restrict__ cand_cnt, const int* __restrict__ cand_list,
                        int* __restrict__ idx) {
  const int n = blockIdx.x;
  const int l = threadIdx.x;  // 64
  const int c = cand_cnt[n];
  if (c == 1) {
    if (l == 0) idx[n] = cand_list[n * 16];
    return;
  }
  const float* zr = flatT + (size_t)n * DIM;
  double zs = 0.0;
  for (int d = l; d < DIM; d += 64) { double v = zr[d]; zs += v * v; }
#pragma unroll
  for (int o = 32; o; o >>= 1) zs += __shfl_xor(zs, o, 64);
  double zn = fmax(sqrt(zs), 1e-12);
  double best = 1e300;
  int bestk = 0x7fffffff;
  const int m = (c < 0) ? KC : c;
  for (int ci = 0; ci < m; ++ci) {
    int k = (c < 0) ? ci : cand_list[n * 16 + ci];
    const float* er = emb + (size_t)k * DIM;
    double cs = 0.0, dot = 0.0;
    for (int d = l; d < DIM; d += 64) {
      double e = er[d], zv = zr[d];
      cs += e * e; dot += zv * e;
    }
#pragma unroll
    for (int o = 32; o; o >>= 1) { cs += __shfl_xor(cs, o, 64); dot += __shfl_xor(dot, o, 64); }
    double cn = fmax(sqrt(cs), 1e-12);
    double score = cs / (cn * cn) - 2.0 * dot / (zn * cn);  // distance minus row-const zsq
    if (score < best || (score == best && k < bestk)) { best = score; bestk = k; }
  }
  if (l == 0) idx[n] = bestk;
}

// ---------------- K7: commitment-loss partials + EMA stats (atomics) ----------------
__global__ void k_stats(const float* __restrict__ flatT, const float* __restrict__ rnorm,
                        const int* __restrict__ idx, float* __restrict__ enc_sum,
                        float* __restrict__ n_total, double* __restrict__ cl_part) {
  const int n = blockIdx.x;
  const int t = threadIdx.x;  // 256
  const int j = idx[n];
  const float rn = rnorm[n], rj = rnorm[j];
  const float* zr  = flatT + (size_t)n * DIM;
  const float* zjr = flatT + (size_t)j * DIM;
  double cl = 0.0;
#pragma unroll
  for (int i = 0; i < 2; ++i) {
    int d = t + i * 256;
    float zv = zr[d] * rn;
    float evv = zjr[d] * rj;
    float df = zv - evv;
    cl += (double)df * (double)df;
    atomicAdd(&enc_sum[(size_t)j * DIM + d], zv);
  }
#pragma unroll
  for (int o = 32; o; o >>= 1) cl += __shfl_xor(cl, o, 64);
  __shared__ double red[4];
  if ((t & 63) == 0) red[t >> 6] = cl;
  __syncthreads();
  if (t == 0) {
    cl_part[n] = red[0] + red[1] + red[2] + red[3];
    atomicAdd(&n_total[j], 1.0f);
  }
}

// ---------------- K8: fused tail — z_avg_new, N_new, embeddings_new, |.| partials ----
// n = sum(N_new); recomputed redundantly per block from the 16 KB L2-resident
// Nb/ntot vectors (replaces the serial single-block k_nnew + k_zavg + k_embnew).
__global__ void k_tail(const float* __restrict__ za, const float* __restrict__ es,
                       const float* __restrict__ Nb, const float* __restrict__ ntot,
                       float* __restrict__ out_zav, float* __restrict__ outN,
                       float* __restrict__ out_emb, double* __restrict__ cbs_part) {
  const int k = blockIdx.x;   // 2048
  const int t = threadIdx.x;  // 256
  const int lane = t & 63, wid = t >> 6;
  float s = 0.f;
#pragma unroll
  for (int i = 0; i < 8; ++i) {
    int kk = t + i * 256;
    s += 0.99f * Nb[kk] + 0.01f * ntot[kk];
  }
#pragma unroll
  for (int o = 32; o; o >>= 1) s += __shfl_xor(s, o, 64);
  __shared__ float redn[4];
  if (lane == 0) redn[wid] = s;
  __syncthreads();
  const float nv = redn[0] + redn[1] + redn[2] + redn[3];
  const float Nn = 0.99f * Nb[k] + 0.01f * ntot[k];
  if (t == 0) outN[k] = Nn;
  const float w = (Nn + 1e-5f) / (nv + 0.02048f) * nv;
  double a = 0.0;
#pragma unroll
  for (int i = 0; i < 2; ++i) {
    size_t gi = (size_t)k * DIM + t + i * 256;
    float zv = 0.99f * za[gi] + 0.01f * es[gi];
    out_zav[gi] = zv;
    float e = zv / w;
    out_emb[gi] = e;
    a += (double)fabsf(e);
  }
#pragma unroll
  for (int o = 32; o; o >>= 1) a += __shfl_xor(a, o, 64);
  __shared__ double red[4];
  if (lane == 0) red[wid] = a;
  __syncthreads();
  if (t == 0) cbs_part[k] = red[0] + red[1] + red[2] + red[3];
}

// ---------------- K9: q gather + (extra block) final scalar reductions ----------------
__global__ void k_q(const float* __restrict__ flatT, const float* __restrict__ rnorm,
                    const int* __restrict__ idx, float* __restrict__ out,
                    const double* __restrict__ cl_part, const double* __restrict__ cbs_part) {
  if (blockIdx.x == 32768) {
    const int t = threadIdx.x;  // 256
    double cl = 0.0, cb = 0.0;
    for (int i = t; i < NROW; i += 256) cl += cl_part[i];
    for (int i = t; i < KC; i += 256) cb += cbs_part[i];
#pragma unroll
    for (int o = 32; o; o >>= 1) { cl += __shfl_xor(cl, o, 64); cb += __shfl_xor(cb, o, 64); }
    __shared__ double redc[4], redb[4];
    if ((t & 63) == 0) { redc[t >> 6] = cl; redb[t >> 6] = cb; }
    __syncthreads();
    if (t == 0) {
      double clm = (redc[0] + redc[1] + redc[2] + redc[3]) / 8388608.0;  // N*D
      double cbs = redb[0] + redb[1] + redb[2] + redb[3];
      out[41943040] = (float)clm;          // commitment_loss
      out[41943041] = (float)(0.25 * clm); // loss = BETA * commitment_loss
      out[41943042] = (float)cbs;          // codebook_sum
    }
    return;
  }
  const int o = blockIdx.x * 256 + threadIdx.x;
  const int b = o >> 19;            // D*H*W = 2^19
  const int d = (o >> 10) & 511;
  const int p = o & 1023;
  const int j = idx[(b << 10) + p];
  out[o] = flatT[(size_t)j * DIM + d] * rnorm[j];
}

// ---------------- launcher ----------------
extern "C" void kernel_launch(void* const* d_in, const int* in_sizes, int n_in,
                              void* d_out, int out_size, void* d_ws, size_t ws_size,
                              hipStream_t stream) {
  const float* z   = (const float*)d_in[0];
  const float* emb = (const float*)d_in[1];
  const float* Nb  = (const float*)d_in[2];
  const float* za  = (const float*)d_in[3];
  float* out = (float*)d_out;
  char*  ws  = (char*)d_ws;

  // workspace layout (bytes)
  float*          flatT     = (float*)(ws + 0);          // 33554432
  unsigned short* cb_bf     = (unsigned short*)(ws + 33554432); // 2097152
  float*          csq       = (float*)(ws + 35651584);   // 8192
  float*          rnorm     = (float*)(ws + 35659776);   // 65536
  int*            idx       = (int*)(ws + 35725312);     // 65536
  int*            cand_cnt  = (int*)(ws + 35790848);     // 65536
  int*            cand_list = (int*)(ws + 35856384);     // 1048576
  double*         cl_part   = (double*)(ws + 36904960);  // 131072
  double*         cbs_part  = (double*)(ws + 37036032);  // 32768 (2048 used)
  float*          enc_sum   = (float*)(ws + 37068800);   // 4194304 (zeroed)
  float*          n_total   = (float*)(ws + 41263104);   // 8192    (zeroed)

  // d_out regions (floats): q[0..8388608), dp[8388608..41943040),
  // scalars[41943040..3), emb_new[41943043), N_new[42991619), z_avg_new[42993667)
  unsigned short* z_bf  = (unsigned short*)out;   // q region reused as bf16 scratch
  float* S        = out + 8388608;
  float* out_emb  = out + 41943043;
  float* out_N    = out + 42991619;
  float* out_zav  = out + 42993667;

  hipMemsetAsync(ws + 37068800, 0, 4202496, stream);   // enc_sum + n_total

  k_cbnorm   <<<KC, 256, 0, stream>>>(emb, cb_bf, csq);
  k_transpose<<<dim3(16, 32, 16), 256, 0, stream>>>(z, flatT);
  k_rownorm  <<<NROW, 256, 0, stream>>>(flatT, rnorm, z_bf);
  k_gemm     <<<dim3(NROW / 128, KC / 128), 256, 0, stream>>>(z_bf, cb_bf, S);
  k_softmax  <<<NROW, 256, 0, stream>>>(S, csq, cand_cnt, cand_list);
  k_fixup    <<<NROW, 64, 0, stream>>>(flatT, emb, cand_cnt, cand_list, idx);
  k_stats    <<<NROW, 256, 0, stream>>>(flatT, rnorm, idx, enc_sum, n_total, cl_part);
  k_tail     <<<KC, 256, 0, stream>>>(za, enc_sum, Nb, n_total, out_zav, out_N, out_emb, cbs_part);
  k_q        <<<32769, 256, 0, stream>>>(flatT, rnorm, idx, out, cl_part, cbs_part);
}